// Round 11
// baseline (106.161 us; speedup 1.0000x reference)
//
#include <hip/hip_runtime.h>
#include <math.h>

#define HIDDEN 256
#define CHUNK 8

typedef float fx4 __attribute__((ext_vector_type(4)));

// Kernel 1: build segment boundary array starts[0..G] from sorted batch ids.
__global__ __launch_bounds__(256) void seg_starts_kernel(
    const int* __restrict__ batch, int* __restrict__ starts, int N, int G) {
  int i = blockIdx.x * blockDim.x + threadIdx.x;
  if (i >= N) return;
  int b = batch[i];
  int prev = (i == 0) ? -1 : batch[i - 1];
  for (int g = prev + 1; g <= b; ++g) starts[g] = i;
  if (i == N - 1) {
    for (int g = b + 1; g <= G; ++g) starts[g] = N;
  }
}

// Kernel 2: block = 4 waves = 1 graph; each wave takes a quarter of the
// graph's chunks; masked remainder chunk; 4 online-softmax states merged via
// LDS. (R6/R10 structure, 97.7 us.) This round's single A/B variable: plain
// loads instead of __builtin_nontemporal_load on the h stream.
__global__ __launch_bounds__(256) void pool_kernel(
    const float* __restrict__ h, const float* __restrict__ node_mult,
    const float* __restrict__ pressure, const float* __restrict__ attn_weight,
    const float* __restrict__ attn_bias, const float* __restrict__ W_pressure,
    const int* __restrict__ starts, float* __restrict__ out, int G) {
  const int q    = threadIdx.x >> 6;   // wave 0..3 = quarter index
  const int lane = threadIdx.x & 63;
  const int g = blockIdx.x;

  __shared__ float s_m[3], s_d[3], s_t[3];
  __shared__ fx4 s_attn[3][64], s_mean[3][64], s_max[3][64];

  const int start = starts[g];
  const int end   = starts[g + 1];
  const int total = end - start;
  const int nfull = total / CHUNK;          // full chunks
  const int rem   = total - nfull * CHUNK;  // 0..7
  const int nt    = nfull + (rem > 0);      // total chunks incl. masked

  const fx4 w4 = *reinterpret_cast<const fx4*>(attn_weight + 4 * lane);
  const float bias = attn_bias[0];

  fx4 attn  = (fx4)(0.f);
  fx4 meanv = (fx4)(0.f);
  fx4 maxv  = (fx4)(-INFINITY);
  float m = -INFINITY;
  float denom = 0.f;
  float tmult = 0.f;

  // this wave's chunk range [c_lo, c_hi) over all nt chunks
  const int c_lo = (q * nt) / 4;
  const int c_hi = ((q + 1) * nt) / 4;
  const int f_hi = (c_hi < nfull) ? c_hi : nfull;  // full-chunk part

  for (int c = c_lo; c < f_hi; ++c) {
    const int i = start + c * CHUNK;
    fx4 hv[CHUNK];
    float mult[CHUNK];
#pragma unroll
    for (int j = 0; j < CHUNK; ++j) {
      hv[j] = *reinterpret_cast<const fx4*>(h + (size_t)(i + j) * HIDDEN + 4 * lane);
      mult[j] = node_mult[i + j];
    }

    float p[CHUNK];
#pragma unroll
    for (int j = 0; j < CHUNK; ++j)
      p[j] = hv[j].x * w4.x + hv[j].y * w4.y + hv[j].z * w4.z + hv[j].w * w4.w;

#pragma unroll
    for (int off = 32; off >= 1; off >>= 1) {
#pragma unroll
      for (int j = 0; j < CHUNK; ++j) p[j] += __shfl_xor(p[j], off, 64);
    }

    float s[CHUNK];
#pragma unroll
    for (int j = 0; j < CHUNK; ++j)
      s[j] = p[j] + bias + __logf(fmaxf(mult[j], 1.f));

    float cmax = s[0];
#pragma unroll
    for (int j = 1; j < CHUNK; ++j) cmax = fmaxf(cmax, s[j]);

    if (cmax > m) {
      const float scale = __expf(m - cmax);  // m=-inf -> 0
      denom *= scale;
      attn *= scale;
      m = cmax;
    }

#pragma unroll
    for (int j = 0; j < CHUNK; ++j) {
      const float e = __expf(s[j] - m);
      denom += e;
      attn += hv[j] * e;
      meanv += hv[j] * mult[j];
      maxv.x = fmaxf(maxv.x, hv[j].x);  maxv.y = fmaxf(maxv.y, hv[j].y);
      maxv.z = fmaxf(maxv.z, hv[j].z);  maxv.w = fmaxf(maxv.w, hv[j].w);
      tmult += mult[j];
    }
  }

  // masked remainder chunk (1..7 nodes), owned by the wave whose range has it
  if (rem > 0 && c_lo <= nfull && nfull < c_hi) {
    const int base = start + nfull * CHUNK;
    fx4 hv[CHUNK];
    float mult[CHUNK];
#pragma unroll
    for (int j = 0; j < CHUNK; ++j) {
      const int idx = base + ((j < rem) ? j : rem - 1);  // clamped, in-bounds
      hv[j] = *reinterpret_cast<const fx4*>(h + (size_t)idx * HIDDEN + 4 * lane);
      mult[j] = (j < rem) ? node_mult[base + j] : 0.f;
    }

    float p[CHUNK];
#pragma unroll
    for (int j = 0; j < CHUNK; ++j)
      p[j] = hv[j].x * w4.x + hv[j].y * w4.y + hv[j].z * w4.z + hv[j].w * w4.w;

#pragma unroll
    for (int off = 32; off >= 1; off >>= 1) {
#pragma unroll
      for (int j = 0; j < CHUNK; ++j) p[j] += __shfl_xor(p[j], off, 64);
    }

    float s[CHUNK];
#pragma unroll
    for (int j = 0; j < CHUNK; ++j)
      s[j] = (j < rem) ? (p[j] + bias + __logf(fmaxf(mult[j], 1.f))) : -INFINITY;

    float cmax = s[0];
#pragma unroll
    for (int j = 1; j < CHUNK; ++j) cmax = fmaxf(cmax, s[j]);

    if (cmax > m) {
      const float scale = __expf(m - cmax);
      denom *= scale;
      attn *= scale;
      m = cmax;
    }

#pragma unroll
    for (int j = 0; j < CHUNK; ++j) {
      const float e = __expf(s[j] - m);  // padded: exp(-inf)=0
      denom += e;
      attn += hv[j] * e;
      meanv += hv[j] * mult[j];          // padded: mult=0
      const bool v2 = (j < rem);
      maxv.x = fmaxf(maxv.x, v2 ? hv[j].x : -INFINITY);
      maxv.y = fmaxf(maxv.y, v2 ? hv[j].y : -INFINITY);
      maxv.z = fmaxf(maxv.z, v2 ? hv[j].z : -INFINITY);
      maxv.w = fmaxf(maxv.w, v2 ? hv[j].w : -INFINITY);
      tmult += mult[j];
    }
  }

  // waves 1..3 publish; wave 0 merges and writes output
  if (q > 0) {
    if (lane == 0) { s_m[q - 1] = m; s_d[q - 1] = denom; s_t[q - 1] = tmult; }
    s_attn[q - 1][lane] = attn;
    s_mean[q - 1][lane] = meanv;
    s_max[q - 1][lane]  = maxv;
  }
  __syncthreads();

  if (q == 0) {
    float M = m, D = denom, T = tmult;
    fx4 A = attn, Me = meanv, Mx = maxv;
#pragma unroll
    for (int k = 0; k < 3; ++k) {
      const float mk = s_m[k];
      const float Mn = fmaxf(M, mk);
      const float sc0 = (M  == -INFINITY) ? 0.f : __expf(M  - Mn);
      const float sck = (mk == -INFINITY) ? 0.f : __expf(mk - Mn);
      D = D * sc0 + s_d[k] * sck;
      A = A * sc0 + s_attn[k][lane] * sck;
      M = Mn;
      Me += s_mean[k][lane];
      const fx4 mxk = s_max[k][lane];
      Mx.x = fmaxf(Mx.x, mxk.x);  Mx.y = fmaxf(Mx.y, mxk.y);
      Mx.z = fmaxf(Mx.z, mxk.z);  Mx.w = fmaxf(Mx.w, mxk.w);
      T += s_t[k];
    }

    const float inv_tm  = 1.f / fmaxf(T, 1e-8f);
    const float inv_den = (D > 0.f) ? 1.f / D : 0.f;
    const float p_norm  = pressure[g] * (1.f / 300.f);
    const fx4 wp4 = *reinterpret_cast<const fx4*>(W_pressure + 4 * lane);

    fx4 res = 0.5f * (Me * inv_tm + A * inv_den) + p_norm * wp4;

    float* outg = out + (size_t)g * (2 * HIDDEN);
    *reinterpret_cast<fx4*>(outg + 4 * lane) = res;
    *reinterpret_cast<fx4*>(outg + HIDDEN + 4 * lane) = Mx;
  }
}

extern "C" void kernel_launch(void* const* d_in, const int* in_sizes, int n_in,
                              void* d_out, int out_size, void* d_ws, size_t ws_size,
                              hipStream_t stream) {
  const float* h           = (const float*)d_in[0];
  const float* node_mult   = (const float*)d_in[1];
  const float* pressure    = (const float*)d_in[2];
  const float* attn_weight = (const float*)d_in[3];
  const float* attn_bias   = (const float*)d_in[4];
  const float* W_pressure  = (const float*)d_in[5];
  const int*   batch       = (const int*)d_in[6];

  const int N = in_sizes[1];
  const int G = in_sizes[2];

  int* starts = (int*)d_ws;
  float* out = (float*)d_out;

  seg_starts_kernel<<<(N + 255) / 256, 256, 0, stream>>>(batch, starts, N, G);
  pool_kernel<<<G, 256, 0, stream>>>(h, node_mult, pressure,
                                     attn_weight, attn_bias,
                                     W_pressure, starts, out, G);
}

// Round 12
// 97.708 us; speedup vs baseline: 1.0865x; 1.0865x over previous
//
#include <hip/hip_runtime.h>
#include <math.h>

#define HIDDEN 256
#define CHUNK 8

typedef float fx4 __attribute__((ext_vector_type(4)));

// Kernel 1: build segment boundary array starts[0..G] from sorted batch ids.
__global__ __launch_bounds__(256) void seg_starts_kernel(
    const int* __restrict__ batch, int* __restrict__ starts, int N, int G) {
  int i = blockIdx.x * blockDim.x + threadIdx.x;
  if (i >= N) return;
  int b = batch[i];
  int prev = (i == 0) ? -1 : batch[i - 1];
  for (int g = prev + 1; g <= b; ++g) starts[g] = i;
  if (i == N - 1) {
    for (int g = b + 1; g <= G; ++g) starts[g] = N;
  }
}

// Kernel 2: block = 4 waves = 1 graph; each wave takes a quarter of the
// graph's chunks; masked remainder chunk; 4 online-softmax states merged via
// LDS. R6/R10 structure WITH nontemporal h loads — measured best (97.7 us).
// A/B history: NT removal +8.5us (R11); 8-wave split +24us (R7); fused
// boundary search +40/+14us (R8/R9); explicit ping-pong +3us (R4).
__global__ __launch_bounds__(256) void pool_kernel(
    const float* __restrict__ h, const float* __restrict__ node_mult,
    const float* __restrict__ pressure, const float* __restrict__ attn_weight,
    const float* __restrict__ attn_bias, const float* __restrict__ W_pressure,
    const int* __restrict__ starts, float* __restrict__ out, int G) {
  const int q    = threadIdx.x >> 6;   // wave 0..3 = quarter index
  const int lane = threadIdx.x & 63;
  const int g = blockIdx.x;

  __shared__ float s_m[3], s_d[3], s_t[3];
  __shared__ fx4 s_attn[3][64], s_mean[3][64], s_max[3][64];

  const int start = starts[g];
  const int end   = starts[g + 1];
  const int total = end - start;
  const int nfull = total / CHUNK;          // full chunks
  const int rem   = total - nfull * CHUNK;  // 0..7
  const int nt    = nfull + (rem > 0);      // total chunks incl. masked

  const fx4 w4 = *reinterpret_cast<const fx4*>(attn_weight + 4 * lane);
  const float bias = attn_bias[0];

  fx4 attn  = (fx4)(0.f);
  fx4 meanv = (fx4)(0.f);
  fx4 maxv  = (fx4)(-INFINITY);
  float m = -INFINITY;
  float denom = 0.f;
  float tmult = 0.f;

  // this wave's chunk range [c_lo, c_hi) over all nt chunks
  const int c_lo = (q * nt) / 4;
  const int c_hi = ((q + 1) * nt) / 4;
  const int f_hi = (c_hi < nfull) ? c_hi : nfull;  // full-chunk part

  for (int c = c_lo; c < f_hi; ++c) {
    const int i = start + c * CHUNK;
    fx4 hv[CHUNK];
    float mult[CHUNK];
#pragma unroll
    for (int j = 0; j < CHUNK; ++j) {
      hv[j] = __builtin_nontemporal_load(
          reinterpret_cast<const fx4*>(h + (size_t)(i + j) * HIDDEN + 4 * lane));
      mult[j] = node_mult[i + j];
    }

    float p[CHUNK];
#pragma unroll
    for (int j = 0; j < CHUNK; ++j)
      p[j] = hv[j].x * w4.x + hv[j].y * w4.y + hv[j].z * w4.z + hv[j].w * w4.w;

#pragma unroll
    for (int off = 32; off >= 1; off >>= 1) {
#pragma unroll
      for (int j = 0; j < CHUNK; ++j) p[j] += __shfl_xor(p[j], off, 64);
    }

    float s[CHUNK];
#pragma unroll
    for (int j = 0; j < CHUNK; ++j)
      s[j] = p[j] + bias + __logf(fmaxf(mult[j], 1.f));

    float cmax = s[0];
#pragma unroll
    for (int j = 1; j < CHUNK; ++j) cmax = fmaxf(cmax, s[j]);

    if (cmax > m) {
      const float scale = __expf(m - cmax);  // m=-inf -> 0
      denom *= scale;
      attn *= scale;
      m = cmax;
    }

#pragma unroll
    for (int j = 0; j < CHUNK; ++j) {
      const float e = __expf(s[j] - m);
      denom += e;
      attn += hv[j] * e;
      meanv += hv[j] * mult[j];
      maxv.x = fmaxf(maxv.x, hv[j].x);  maxv.y = fmaxf(maxv.y, hv[j].y);
      maxv.z = fmaxf(maxv.z, hv[j].z);  maxv.w = fmaxf(maxv.w, hv[j].w);
      tmult += mult[j];
    }
  }

  // masked remainder chunk (1..7 nodes), owned by the wave whose range has it
  if (rem > 0 && c_lo <= nfull && nfull < c_hi) {
    const int base = start + nfull * CHUNK;
    fx4 hv[CHUNK];
    float mult[CHUNK];
#pragma unroll
    for (int j = 0; j < CHUNK; ++j) {
      const int idx = base + ((j < rem) ? j : rem - 1);  // clamped, in-bounds
      hv[j] = __builtin_nontemporal_load(
          reinterpret_cast<const fx4*>(h + (size_t)idx * HIDDEN + 4 * lane));
      mult[j] = (j < rem) ? node_mult[base + j] : 0.f;
    }

    float p[CHUNK];
#pragma unroll
    for (int j = 0; j < CHUNK; ++j)
      p[j] = hv[j].x * w4.x + hv[j].y * w4.y + hv[j].z * w4.z + hv[j].w * w4.w;

#pragma unroll
    for (int off = 32; off >= 1; off >>= 1) {
#pragma unroll
      for (int j = 0; j < CHUNK; ++j) p[j] += __shfl_xor(p[j], off, 64);
    }

    float s[CHUNK];
#pragma unroll
    for (int j = 0; j < CHUNK; ++j)
      s[j] = (j < rem) ? (p[j] + bias + __logf(fmaxf(mult[j], 1.f))) : -INFINITY;

    float cmax = s[0];
#pragma unroll
    for (int j = 1; j < CHUNK; ++j) cmax = fmaxf(cmax, s[j]);

    if (cmax > m) {
      const float scale = __expf(m - cmax);
      denom *= scale;
      attn *= scale;
      m = cmax;
    }

#pragma unroll
    for (int j = 0; j < CHUNK; ++j) {
      const float e = __expf(s[j] - m);  // padded: exp(-inf)=0
      denom += e;
      attn += hv[j] * e;
      meanv += hv[j] * mult[j];          // padded: mult=0
      const bool v2 = (j < rem);
      maxv.x = fmaxf(maxv.x, v2 ? hv[j].x : -INFINITY);
      maxv.y = fmaxf(maxv.y, v2 ? hv[j].y : -INFINITY);
      maxv.z = fmaxf(maxv.z, v2 ? hv[j].z : -INFINITY);
      maxv.w = fmaxf(maxv.w, v2 ? hv[j].w : -INFINITY);
      tmult += mult[j];
    }
  }

  // waves 1..3 publish; wave 0 merges and writes output
  if (q > 0) {
    if (lane == 0) { s_m[q - 1] = m; s_d[q - 1] = denom; s_t[q - 1] = tmult; }
    s_attn[q - 1][lane] = attn;
    s_mean[q - 1][lane] = meanv;
    s_max[q - 1][lane]  = maxv;
  }
  __syncthreads();

  if (q == 0) {
    float M = m, D = denom, T = tmult;
    fx4 A = attn, Me = meanv, Mx = maxv;
#pragma unroll
    for (int k = 0; k < 3; ++k) {
      const float mk = s_m[k];
      const float Mn = fmaxf(M, mk);
      const float sc0 = (M  == -INFINITY) ? 0.f : __expf(M  - Mn);
      const float sck = (mk == -INFINITY) ? 0.f : __expf(mk - Mn);
      D = D * sc0 + s_d[k] * sck;
      A = A * sc0 + s_attn[k][lane] * sck;
      M = Mn;
      Me += s_mean[k][lane];
      const fx4 mxk = s_max[k][lane];
      Mx.x = fmaxf(Mx.x, mxk.x);  Mx.y = fmaxf(Mx.y, mxk.y);
      Mx.z = fmaxf(Mx.z, mxk.z);  Mx.w = fmaxf(Mx.w, mxk.w);
      T += s_t[k];
    }

    const float inv_tm  = 1.f / fmaxf(T, 1e-8f);
    const float inv_den = (D > 0.f) ? 1.f / D : 0.f;
    const float p_norm  = pressure[g] * (1.f / 300.f);
    const fx4 wp4 = *reinterpret_cast<const fx4*>(W_pressure + 4 * lane);

    fx4 res = 0.5f * (Me * inv_tm + A * inv_den) + p_norm * wp4;

    float* outg = out + (size_t)g * (2 * HIDDEN);
    *reinterpret_cast<fx4*>(outg + 4 * lane) = res;
    *reinterpret_cast<fx4*>(outg + HIDDEN + 4 * lane) = Mx;
  }
}

extern "C" void kernel_launch(void* const* d_in, const int* in_sizes, int n_in,
                              void* d_out, int out_size, void* d_ws, size_t ws_size,
                              hipStream_t stream) {
  const float* h           = (const float*)d_in[0];
  const float* node_mult   = (const float*)d_in[1];
  const float* pressure    = (const float*)d_in[2];
  const float* attn_weight = (const float*)d_in[3];
  const float* attn_bias   = (const float*)d_in[4];
  const float* W_pressure  = (const float*)d_in[5];
  const int*   batch       = (const int*)d_in[6];

  const int N = in_sizes[1];
  const int G = in_sizes[2];

  int* starts = (int*)d_ws;
  float* out = (float*)d_out;

  seg_starts_kernel<<<(N + 255) / 256, 256, 0, stream>>>(batch, starts, N, G);
  pool_kernel<<<G, 256, 0, stream>>>(h, node_mult, pressure,
                                     attn_weight, attn_bias,
                                     W_pressure, starts, out, G);
}